// Round 11
// baseline (929.548 us; speedup 1.0000x reference)
//
#include <hip/hip_runtime.h>

#define NODES   30000
#define E0N     480000
#define ETOT    510000   // E0N + NODES self loops
#define D0      100
#define WDIM    300      // H*F = 3*100
#define NW      600      // dual output width
#define NEG     0.2f
#define AROWS   30080    // 235*128 padded rows for frag buffers
#define AK      320      // padded K

typedef __bf16 bf16x8 __attribute__((ext_vector_type(8)));
typedef float  f32x4  __attribute__((ext_vector_type(4)));

// ---------------- CSR build ----------------
__global__ void count_edges(const int* __restrict__ ei, int* __restrict__ counts) {
    int e = blockIdx.x * 256 + threadIdx.x;
    if (e >= ETOT) return;
    int d = (e < E0N) ? ei[E0N + e] : (e - E0N);
    atomicAdd(&counts[d], 1);
}

__global__ __launch_bounds__(1024) void scan_kernel(const int* __restrict__ counts,
                                                    int* __restrict__ offsets, int n) {
    __shared__ int lds[1024];
    const int CH = 32;
    int t = threadIdx.x;
    int base = t * CH;
    int loc[CH];
    int sum = 0;
    #pragma unroll
    for (int i = 0; i < CH; i++) {
        int v = (base + i < n) ? counts[base + i] : 0;
        loc[i] = sum;
        sum += v;
    }
    lds[t] = sum;
    __syncthreads();
    for (int off = 1; off < 1024; off <<= 1) {
        int v = (t >= off) ? lds[t - off] : 0;
        __syncthreads();
        lds[t] += v;
        __syncthreads();
    }
    int ex = (t == 0) ? 0 : lds[t - 1];
    #pragma unroll
    for (int i = 0; i < CH; i++) {
        int idx = base + i;
        if (idx < n) offsets[idx] = ex + loc[i];
    }
    if (t == 0) offsets[n] = lds[1023];
}

__global__ void scatter_edges(const int* __restrict__ ei, const int* __restrict__ offsets,
                              int* __restrict__ cursor, int* __restrict__ csr_src) {
    int e = blockIdx.x * 256 + threadIdx.x;
    if (e >= ETOT) return;
    int s, d;
    if (e < E0N) { s = ei[e]; d = ei[E0N + e]; }
    else         { s = e - E0N; d = s; }
    int pos = offsets[d] + atomicAdd(&cursor[d], 1);
    csr_src[pos] = s;
}

// ---------------- all-layer B fragment pre-split (one launch) ----------------
__device__ __forceinline__ void bfrag_one(const float* Bl, const float* Br,
                                          bf16x8* out, int K, int t) {
    int lane = t & 63;
    int n16  = (t >> 6) % 40;
    int s    = t / (64 * 40);
    int c = n16 * 16 + (lane & 15);
    union { bf16x8 v; __bf16 e[8]; } hi, lo;
    #pragma unroll
    for (int j = 0; j < 8; j++) {
        int k = s * 32 + ((lane >> 4) * 8) + j;
        float x = 0.f;
        if (k < K && c < NW)
            x = (c < WDIM) ? Bl[(size_t)k * WDIM + c] : Br[(size_t)k * WDIM + c - WDIM];
        __bf16 h = (__bf16)x;
        hi.e[j] = h;
        lo.e[j] = (__bf16)(x - (float)h);
    }
    size_t base = ((size_t)(s * 40 + n16) * 2) * 64 + lane;
    out[base]      = hi.v;
    out[base + 64] = lo.v;
}

__global__ void make_bfrag_all(const float* __restrict__ Wl0, const float* __restrict__ Wr0,
                               const float* __restrict__ Wl, const float* __restrict__ Wr,
                               bf16x8* __restrict__ frag0, bf16x8* __restrict__ frag1,
                               size_t fragstride) {
    int t = blockIdx.x * 256 + threadIdx.x;
    const int L0 = 4 * 40 * 64, LN = 10 * 40 * 64;
    if (t < L0) {
        bfrag_one(Wl0, Wr0, frag0, D0, t);
    } else {
        int u = t - L0;
        int layer = u / LN;
        if (layer >= 4) return;
        bfrag_one(Wl + (size_t)layer * WDIM * WDIM, Wr + (size_t)layer * WDIM * WDIM,
                  frag1 + layer * fragstride, WDIM, u - layer * LN);
    }
}

// ---------------- layer-0 MFMA GEMM: A = emb[xmap[row]] (f32, inline split) ----
__global__ __launch_bounds__(256) void gemm_emb(
    const float* __restrict__ A, const int* __restrict__ xmap,
    const bf16x8* __restrict__ Bfrag,
    const float* __restrict__ bl, const float* __restrict__ br,
    float* __restrict__ Cl, float* __restrict__ Cr,
    int M, int K, int ksteps) {

    __shared__ bf16x8 Alds[8][2][64];
    __shared__ bf16x8 Blds[8][2][64];

    int id = blockIdx.x;
    int mb = (id & 7) + 8 * (id / 40);
    int cb = (id >> 3) % 5;
    if (mb >= 235) return;

    int tid  = threadIdx.x;
    int lane = tid & 63;
    int wid  = tid >> 6;
    int wm = wid >> 1, wn = wid & 1;
    int row0 = mb * 128;

    f32x4 acc[4][4] = {};

    for (int s = 0; s < ksteps; s++) {
        int kt = s * 32;
        #pragma unroll
        for (int u0 = 0; u0 < 2; u0++) {
            int u = u0 * 256 + tid;
            int m16  = u >> 6;
            int slot = u & 63;
            int kh = slot >> 4, rl = slot & 15;
            int gr = row0 + m16 * 16 + rl;
            int gc = kt + kh * 8;
            float4 v0 = make_float4(0.f,0.f,0.f,0.f), v1 = v0;
            if (gr < M) {
                int ar = xmap[gr];
                const float* ap = A + (size_t)ar * K + gc;
                if (gc + 4 <= K) v0 = *(const float4*)ap;
                if (gc + 8 <= K) v1 = *(const float4*)(ap + 4);
            }
            union { bf16x8 v; __bf16 e[8]; } hi, lo;
            const float* xs0 = (const float*)&v0;
            const float* xs1 = (const float*)&v1;
            #pragma unroll
            for (int j = 0; j < 8; j++) {
                float x = (j < 4) ? xs0[j] : xs1[j - 4];
                __bf16 h = (__bf16)x;
                hi.e[j] = h;
                lo.e[j] = (__bf16)(x - (float)h);
            }
            Alds[m16][0][slot] = hi.v;
            Alds[m16][1][slot] = lo.v;
        }
        {
            const float4* bsrc = (const float4*)(Bfrag + ((size_t)(s * 40 + cb * 8) * 2) * 64);
            float4* bdst = (float4*)&Blds[0][0][0];
            #pragma unroll
            for (int c = 0; c < 4; c++)
                bdst[c * 256 + tid] = bsrc[c * 256 + tid];
        }
        __syncthreads();

        bf16x8 af[4][2], bfr[4][2];
        #pragma unroll
        for (int m = 0; m < 4; m++) {
            af[m][0] = Alds[wm * 4 + m][0][lane];
            af[m][1] = Alds[wm * 4 + m][1][lane];
        }
        #pragma unroll
        for (int n = 0; n < 4; n++) {
            bfr[n][0] = Blds[wn * 4 + n][0][lane];
            bfr[n][1] = Blds[wn * 4 + n][1][lane];
        }
        #pragma unroll
        for (int m = 0; m < 4; m++)
            #pragma unroll
            for (int n = 0; n < 4; n++) {
                acc[m][n] = __builtin_amdgcn_mfma_f32_16x16x32_bf16(af[m][1], bfr[n][0], acc[m][n], 0, 0, 0);
                acc[m][n] = __builtin_amdgcn_mfma_f32_16x16x32_bf16(af[m][0], bfr[n][1], acc[m][n], 0, 0, 0);
                acc[m][n] = __builtin_amdgcn_mfma_f32_16x16x32_bf16(af[m][0], bfr[n][0], acc[m][n], 0, 0, 0);
            }
        __syncthreads();
    }

    int r0 = row0 + wm * 64;
    int c0 = cb * 128 + wn * 64;
    #pragma unroll
    for (int m = 0; m < 4; m++)
        #pragma unroll
        for (int n = 0; n < 4; n++) {
            #pragma unroll
            for (int reg = 0; reg < 4; reg++) {
                int gr = r0 + m * 16 + (lane >> 4) * 4 + reg;
                int gc = c0 + n * 16 + (lane & 15);
                if (gr < M && gc < NW) {
                    bool left = gc < WDIM;
                    int cc = left ? gc : gc - WDIM;
                    float v = acc[m][n][reg] + (left ? bl[cc] : br[cc]);
                    (left ? Cl : Cr)[(size_t)gr * WDIM + cc] = v;
                }
            }
        }
}

// ---------------- layers 1-4: A pre-split row-major [AROWS][320] hi/lo bf16 ----
__global__ __launch_bounds__(256) void gemm_frag(
    const ushort* __restrict__ ahi, const ushort* __restrict__ alo,
    const bf16x8* __restrict__ Bfrag,
    const float* __restrict__ bl, const float* __restrict__ br,
    float* __restrict__ Cl, float* __restrict__ Cr, int M) {

    __shared__ bf16x8 Alds[8][2][64];
    __shared__ bf16x8 Blds[8][2][64];

    int id = blockIdx.x;
    int mb = (id & 7) + 8 * (id / 40);
    int cb = (id >> 3) % 5;
    if (mb >= 235) return;

    int tid  = threadIdx.x;
    int lane = tid & 63;
    int wid  = tid >> 6;
    int wm = wid >> 1, wn = wid & 1;
    int row0 = mb * 128;

    f32x4 acc[4][4] = {};

    for (int s = 0; s < 10; s++) {
        int kt = s * 32;
        // A stage: pure 16B copies; per wave 16 rows x 64B contiguous (full sectors)
        #pragma unroll
        for (int u0 = 0; u0 < 2; u0++) {
            int u = u0 * 256 + tid;
            int m16  = u >> 6;
            int slot = u & 63;
            size_t off = (size_t)(row0 + m16 * 16 + (slot & 15)) * AK + kt + (slot >> 4) * 8;
            Alds[m16][0][slot] = *(const bf16x8*)(ahi + off);
            Alds[m16][1][slot] = *(const bf16x8*)(alo + off);
        }
        {
            const float4* bsrc = (const float4*)(Bfrag + ((size_t)(s * 40 + cb * 8) * 2) * 64);
            float4* bdst = (float4*)&Blds[0][0][0];
            #pragma unroll
            for (int c = 0; c < 4; c++)
                bdst[c * 256 + tid] = bsrc[c * 256 + tid];
        }
        __syncthreads();

        bf16x8 af[4][2], bfr[4][2];
        #pragma unroll
        for (int m = 0; m < 4; m++) {
            af[m][0] = Alds[wm * 4 + m][0][lane];
            af[m][1] = Alds[wm * 4 + m][1][lane];
        }
        #pragma unroll
        for (int n = 0; n < 4; n++) {
            bfr[n][0] = Blds[wn * 4 + n][0][lane];
            bfr[n][1] = Blds[wn * 4 + n][1][lane];
        }
        #pragma unroll
        for (int m = 0; m < 4; m++)
            #pragma unroll
            for (int n = 0; n < 4; n++) {
                acc[m][n] = __builtin_amdgcn_mfma_f32_16x16x32_bf16(af[m][1], bfr[n][0], acc[m][n], 0, 0, 0);
                acc[m][n] = __builtin_amdgcn_mfma_f32_16x16x32_bf16(af[m][0], bfr[n][1], acc[m][n], 0, 0, 0);
                acc[m][n] = __builtin_amdgcn_mfma_f32_16x16x32_bf16(af[m][0], bfr[n][0], acc[m][n], 0, 0, 0);
            }
        __syncthreads();
    }

    int r0 = row0 + wm * 64;
    int c0 = cb * 128 + wn * 64;
    #pragma unroll
    for (int m = 0; m < 4; m++)
        #pragma unroll
        for (int n = 0; n < 4; n++) {
            #pragma unroll
            for (int reg = 0; reg < 4; reg++) {
                int gr = r0 + m * 16 + (lane >> 4) * 4 + reg;
                int gc = c0 + n * 16 + (lane & 15);
                if (gr < M && gc < NW) {
                    bool left = gc < WDIM;
                    int cc = left ? gc : gc - WDIM;
                    float v = acc[m][n][reg] + (left ? bl[cc] : br[cc]);
                    (left ? Cl : Cr)[(size_t)gr * WDIM + cc] = v;
                }
            }
        }
}

// ---------------- fused GAT: 2 waves per node, 2-edge ILP, LDS merge ----
// Block = 4 waves = 2 nodes. Wave sub∈{0,1} handles half the node's edges.
// write_frag: epilogue emits hi/lo bf16 [node][320] row-major; else f32 flat.
__global__ __launch_bounds__(256) void gat_edge_agg(
    const float* __restrict__ xl, const float* __restrict__ xr,
    const int* __restrict__ offsets, const int* __restrict__ csr_src,
    const float* __restrict__ att, const float* __restrict__ bias,
    float* __restrict__ fout, ushort* __restrict__ ahi, ushort* __restrict__ alo,
    int write_frag) {
    __shared__ float st[4][64][8];
    int wid  = threadIdx.x >> 6;
    int lane = threadIdx.x & 63;
    int node = blockIdx.x * 2 + (wid >> 1);   // NODES even: always valid
    int sub  = wid & 1;
    int r = lane & 3;
    bool c0 = lane < 50;   // j0: head0 else head1
    bool c1 = lane < 36;   // j1: head1 else head2

    float2 aw2[3], xr2[3];
    const float2* xrrow = (const float2*)(xr + (size_t)node * WDIM);
    #pragma unroll
    for (int j = 0; j < 3; j++) {
        int i = lane + 64 * j;
        if (i < 150) {
            aw2[j].x = att[2 * i]; aw2[j].y = att[2 * i + 1];
            xr2[j] = xrrow[i];
        } else {
            aw2[j].x = 0.f; aw2[j].y = 0.f;
            xr2[j].x = 0.f; xr2[j].y = 0.f;
        }
    }

    float mq = -1e38f, sq = 0.f;
    float2 acc2[3] = {};

    int beg = offsets[node], end = offsets[node + 1];
    int half = (end - beg + 1) >> 1;
    int lo = beg + sub * half;
    int hi = sub ? end : beg + half;

    for (int i = lo; i < hi; i += 2) {
        bool act_b = (i + 1) < hi;
        int sa = csr_src[i];
        int sb = csr_src[act_b ? i + 1 : i];
        const float2* ra = (const float2*)(xl + (size_t)sa * WDIM);
        const float2* rb = (const float2*)(xl + (size_t)sb * WDIM);
        float2 va[3], vb[3];
        va[0] = ra[lane];      vb[0] = rb[lane];
        va[1] = ra[lane + 64]; vb[1] = rb[lane + 64];
        if (lane < 22) { va[2] = ra[lane + 128]; vb[2] = rb[lane + 128]; }
        else { va[2].x = va[2].y = vb[2].x = vb[2].y = 0.f; }

        float qa[3], qb[3];
        #pragma unroll
        for (int j = 0; j < 3; j++) {
            float tax = va[j].x + xr2[j].x; tax = fmaxf(tax, NEG * tax);
            float tay = va[j].y + xr2[j].y; tay = fmaxf(tay, NEG * tay);
            float tbx = vb[j].x + xr2[j].x; tbx = fmaxf(tbx, NEG * tbx);
            float tby = vb[j].y + xr2[j].y; tby = fmaxf(tby, NEG * tby);
            qa[j] = tax * aw2[j].x + tay * aw2[j].y;
            qb[j] = tbx * aw2[j].x + tby * aw2[j].y;
        }
        float pa0 = c0 ? qa[0] : 0.f;
        float pa1 = (c0 ? 0.f : qa[0]) + (c1 ? qa[1] : 0.f);
        float pa2 = (c1 ? 0.f : qa[1]) + qa[2];
        float pb0 = c0 ? qb[0] : 0.f;
        float pb1 = (c0 ? 0.f : qb[0]) + (c1 ? qb[1] : 0.f);
        float pb2 = (c1 ? 0.f : qb[1]) + qb[2];

        pa0 += __shfl_xor(pa0, 1, 64); pa1 += __shfl_xor(pa1, 1, 64); pa2 += __shfl_xor(pa2, 1, 64);
        pb0 += __shfl_xor(pb0, 1, 64); pb1 += __shfl_xor(pb1, 1, 64); pb2 += __shfl_xor(pb2, 1, 64);
        pa0 += __shfl_xor(pa0, 2, 64); pa1 += __shfl_xor(pa1, 2, 64); pa2 += __shfl_xor(pa2, 2, 64);
        pb0 += __shfl_xor(pb0, 2, 64); pb1 += __shfl_xor(pb1, 2, 64); pb2 += __shfl_xor(pb2, 2, 64);
        float sqa = (r == 1) ? pa1 : ((r == 2) ? pa2 : pa0);
        float sqb = (r == 1) ? pb1 : ((r == 2) ? pb2 : pb0);
        sqa += __shfl_xor(sqa, 4, 64);  sqb += __shfl_xor(sqb, 4, 64);
        sqa += __shfl_xor(sqa, 8, 64);  sqb += __shfl_xor(sqb, 8, 64);
        sqa += __shfl_xor(sqa, 16, 64); sqb += __shfl_xor(sqb, 16, 64);
        sqa += __shfl_xor(sqa, 32, 64); sqb += __shfl_xor(sqb, 32, 64);
        if (!act_b) sqb = -3e38f;

        float hiq = fmaxf(sqa, sqb);
        if (__any(hiq > mq + 8.f)) {
            float nmq = fmaxf(mq, hiq);
            float eq = __expf(mq - nmq);
            sq *= eq;
            float e0 = __shfl(eq, 0, 64), e1 = __shfl(eq, 1, 64), e2 = __shfl(eq, 2, 64);
            float ej0 = c0 ? e0 : e1, ej1 = c1 ? e1 : e2;
            acc2[0].x *= ej0; acc2[0].y *= ej0;
            acc2[1].x *= ej1; acc2[1].y *= ej1;
            acc2[2].x *= e2;  acc2[2].y *= e2;
            mq = nmq;
        }
        float cqa = __expf(sqa - mq), cqb = __expf(sqb - mq);
        sq += cqa + cqb;
        float ca0 = __shfl(cqa, 0, 64), ca1 = __shfl(cqa, 1, 64), ca2 = __shfl(cqa, 2, 64);
        float cb0 = __shfl(cqb, 0, 64), cb1 = __shfl(cqb, 1, 64), cb2 = __shfl(cqb, 2, 64);
        float caj[3] = { c0 ? ca0 : ca1, c1 ? ca1 : ca2, ca2 };
        float cbj[3] = { c0 ? cb0 : cb1, c1 ? cb1 : cb2, cb2 };
        #pragma unroll
        for (int j = 0; j < 3; j++) {
            acc2[j].x = fmaf(caj[j], va[j].x, acc2[j].x);
            acc2[j].y = fmaf(caj[j], va[j].y, acc2[j].y);
            acc2[j].x = fmaf(cbj[j], vb[j].x, acc2[j].x);
            acc2[j].y = fmaf(cbj[j], vb[j].y, acc2[j].y);
        }
    }

    // publish partial state
    st[wid][lane][0] = mq;
    st[wid][lane][1] = sq;
    st[wid][lane][2] = acc2[0].x; st[wid][lane][3] = acc2[0].y;
    st[wid][lane][4] = acc2[1].x; st[wid][lane][5] = acc2[1].y;
    st[wid][lane][6] = acc2[2].x; st[wid][lane][7] = acc2[2].y;
    __syncthreads();
    if (sub) return;

    // exact merge with partner wave
    float m1 = st[wid ^ 1][lane][0];
    float s1 = st[wid ^ 1][lane][1];
    float2 o1[3];
    o1[0].x = st[wid ^ 1][lane][2]; o1[0].y = st[wid ^ 1][lane][3];
    o1[1].x = st[wid ^ 1][lane][4]; o1[1].y = st[wid ^ 1][lane][5];
    o1[2].x = st[wid ^ 1][lane][6]; o1[2].y = st[wid ^ 1][lane][7];

    float M  = fmaxf(mq, m1);
    float ea = __expf(mq - M), eb = __expf(m1 - M);
    float sF = sq * ea + s1 * eb;
    float iq = 1.f / sF;
    float ea0 = __shfl(ea, 0, 64), ea1 = __shfl(ea, 1, 64), ea2 = __shfl(ea, 2, 64);
    float eb0 = __shfl(eb, 0, 64), eb1 = __shfl(eb, 1, 64), eb2 = __shfl(eb, 2, 64);
    float i0  = __shfl(iq, 0, 64), i1  = __shfl(iq, 1, 64), i2  = __shfl(iq, 2, 64);
    float eaj[3]  = { c0 ? ea0 : ea1, c1 ? ea1 : ea2, ea2 };
    float ebj[3]  = { c0 ? eb0 : eb1, c1 ? eb1 : eb2, eb2 };
    float isel[3] = { c0 ? i0 : i1,  c1 ? i1 : i2,  i2 };

    #pragma unroll
    for (int j = 0; j < 3; j++) {
        int fi = lane + 64 * j;
        if (fi < 150) {
            float ax = acc2[j].x * eaj[j] + o1[j].x * ebj[j];
            float ay = acc2[j].y * eaj[j] + o1[j].y * ebj[j];
            float ox = fmaxf(ax * isel[j] + bias[2 * fi],     0.f);
            float oy = fmaxf(ay * isel[j] + bias[2 * fi + 1], 0.f);
            if (write_frag) {
                __bf16 hx = (__bf16)ox, hy = (__bf16)oy;
                __bf16 lx = (__bf16)(ox - (float)hx), ly = (__bf16)(oy - (float)hy);
                ushort2 hv, lv;
                hv.x = *(ushort*)&hx; hv.y = *(ushort*)&hy;
                lv.x = *(ushort*)&lx; lv.y = *(ushort*)&ly;
                *(ushort2*)(ahi + (size_t)node * AK + 2 * fi) = hv;
                *(ushort2*)(alo + (size_t)node * AK + 2 * fi) = lv;
            } else {
                float2 o; o.x = ox; o.y = oy;
                *(float2*)(fout + (size_t)node * WDIM + 2 * fi) = o;
            }
        }
    }
}

// ---------------- host ----------------
static inline size_t align256(size_t x) { return (x + 255) & ~(size_t)255; }

extern "C" void kernel_launch(void* const* d_in, const int* in_sizes, int n_in,
                              void* d_out, int out_size, void* d_ws, size_t ws_size,
                              hipStream_t stream) {
    const int*   x     = (const int*)d_in[0];
    const int*   ei    = (const int*)d_in[1];
    const float* emb   = (const float*)d_in[2];
    const float* Wl0   = (const float*)d_in[3];
    const float* bl0   = (const float*)d_in[4];
    const float* Wr0   = (const float*)d_in[5];
    const float* br0   = (const float*)d_in[6];
    const float* att0  = (const float*)d_in[7];
    const float* bias0 = (const float*)d_in[8];
    const float* Wl    = (const float*)d_in[9];
    const float* bl    = (const float*)d_in[10];
    const float* Wr    = (const float*)d_in[11];
    const float* br    = (const float*)d_in[12];
    const float* att   = (const float*)d_in[13];
    const float* bias  = (const float*)d_in[14];

    char* ws = (char*)d_ws;
    size_t off = 0;
    ushort* ahi   = (ushort*)(ws + off); off = align256(off + (size_t)AROWS * AK * 2);
    ushort* alo   = (ushort*)(ws + off); off = align256(off + (size_t)AROWS * AK * 2);
    float* xlb    = (float*)(ws + off);  off = align256(off + (size_t)NODES * WDIM * 4);
    float* xrb    = (float*)(ws + off);  off = align256(off + (size_t)NODES * WDIM * 4);
    int* counts   = (int*)(ws + off);    off = align256(off + (size_t)NODES * 4);
    int* cursor   = (int*)(ws + off);    off = align256(off + (size_t)NODES * 4);
    int* offsets  = (int*)(ws + off);    off = align256(off + (size_t)(NODES + 1) * 4);
    int* csr_src  = (int*)(ws + off);    off = align256(off + (size_t)ETOT * 4);
    size_t frag_l0_elems = (size_t)4 * 40 * 2 * 64;    // bf16x8 units
    size_t frag_ln_elems = (size_t)10 * 40 * 2 * 64;
    bf16x8* bfrag0 = (bf16x8*)(ws + off); off = align256(off + frag_l0_elems * 16);
    bf16x8* bfrag1 = (bf16x8*)(ws + off); off = align256(off + 4 * frag_ln_elems * 16);

    float* out = (float*)d_out;

    // all weight fragment pre-splits in ONE launch
    {
        int total = 4 * 40 * 64 + 4 * 10 * 40 * 64;
        make_bfrag_all<<<(total + 255) / 256, 256, 0, stream>>>(
            Wl0, Wr0, Wl, Wr, bfrag0, bfrag1, frag_ln_elems);
    }

    // CSR build
    hipMemsetAsync(counts, 0, (size_t)NODES * 4, stream);
    hipMemsetAsync(cursor, 0, (size_t)NODES * 4, stream);
    count_edges<<<(ETOT + 255) / 256, 256, 0, stream>>>(ei, counts);
    scan_kernel<<<1, 1024, 0, stream>>>(counts, offsets, NODES);
    scatter_edges<<<(ETOT + 255) / 256, 256, 0, stream>>>(ei, offsets, cursor, csr_src);

    int agg_blocks = NODES / 2;   // 2 nodes per block (NODES even)

    // layer 0: A = emb with row indirection; agg writes hi/lo frag
    gemm_emb<<<1200, 256, 0, stream>>>(emb, x, bfrag0, bl0, br0, xlb, xrb, NODES, D0, 4);
    gat_edge_agg<<<agg_blocks, 256, 0, stream>>>(xlb, xrb, offsets, csr_src, att0, bias0,
                                                 nullptr, ahi, alo, 1);

    // layers 1..4
    for (int i = 0; i < 4; i++) {
        int last = (i == 3);
        gemm_frag<<<1200, 256, 0, stream>>>(ahi, alo, bfrag1 + i * frag_ln_elems,
                                            bl + i * WDIM, br + i * WDIM, xlb, xrb, NODES);
        gat_edge_agg<<<agg_blocks, 256, 0, stream>>>(xlb, xrb, offsets, csr_src,
                                                     att + (size_t)i * WDIM,
                                                     bias + (size_t)i * WDIM,
                                                     last ? out : nullptr, ahi, alo, !last);
    }
}

// Round 12
// 851.458 us; speedup vs baseline: 1.0917x; 1.0917x over previous
//
#include <hip/hip_runtime.h>

#define NODES   30000
#define E0N     480000
#define ETOT    510000   // E0N + NODES self loops
#define D0      100
#define WDIM    300      // H*F = 3*100
#define NW      600      // dual output width
#define NEG     0.2f
#define XLP     320      // padded xl row (bf16 elems), 640B aligned rows

typedef __bf16 bf16x8 __attribute__((ext_vector_type(8)));
typedef float  f32x4  __attribute__((ext_vector_type(4)));

// ---------------- CSR build ----------------
__global__ void count_edges(const int* __restrict__ ei, int* __restrict__ counts) {
    int e = blockIdx.x * 256 + threadIdx.x;
    if (e >= ETOT) return;
    int d = (e < E0N) ? ei[E0N + e] : (e - E0N);
    atomicAdd(&counts[d], 1);
}

__global__ __launch_bounds__(1024) void scan_kernel(const int* __restrict__ counts,
                                                    int* __restrict__ offsets, int n) {
    __shared__ int lds[1024];
    const int CH = 32;
    int t = threadIdx.x;
    int base = t * CH;
    int loc[CH];
    int sum = 0;
    #pragma unroll
    for (int i = 0; i < CH; i++) {
        int v = (base + i < n) ? counts[base + i] : 0;
        loc[i] = sum;
        sum += v;
    }
    lds[t] = sum;
    __syncthreads();
    for (int off = 1; off < 1024; off <<= 1) {
        int v = (t >= off) ? lds[t - off] : 0;
        __syncthreads();
        lds[t] += v;
        __syncthreads();
    }
    int ex = (t == 0) ? 0 : lds[t - 1];
    #pragma unroll
    for (int i = 0; i < CH; i++) {
        int idx = base + i;
        if (idx < n) offsets[idx] = ex + loc[i];
    }
    if (t == 0) offsets[n] = lds[1023];
}

__global__ void scatter_edges(const int* __restrict__ ei, const int* __restrict__ offsets,
                              int* __restrict__ cursor, int* __restrict__ csr_src) {
    int e = blockIdx.x * 256 + threadIdx.x;
    if (e >= ETOT) return;
    int s, d;
    if (e < E0N) { s = ei[e]; d = ei[E0N + e]; }
    else         { s = e - E0N; d = s; }
    int pos = offsets[d] + atomicAdd(&cursor[d], 1);
    csr_src[pos] = s;
}

// ---------------- all-layer B fragment pre-split (one launch) ----------------
__device__ __forceinline__ void bfrag_one(const float* Bl, const float* Br,
                                          bf16x8* out, int K, int t) {
    int lane = t & 63;
    int n16  = (t >> 6) % 40;
    int s    = t / (64 * 40);
    int c = n16 * 16 + (lane & 15);
    union { bf16x8 v; __bf16 e[8]; } hi, lo;
    #pragma unroll
    for (int j = 0; j < 8; j++) {
        int k = s * 32 + ((lane >> 4) * 8) + j;
        float x = 0.f;
        if (k < K && c < NW)
            x = (c < WDIM) ? Bl[(size_t)k * WDIM + c] : Br[(size_t)k * WDIM + c - WDIM];
        __bf16 h = (__bf16)x;
        hi.e[j] = h;
        lo.e[j] = (__bf16)(x - (float)h);
    }
    size_t base = ((size_t)(s * 40 + n16) * 2) * 64 + lane;
    out[base]      = hi.v;
    out[base + 64] = lo.v;
}

__global__ void make_bfrag_all(const float* __restrict__ Wl0, const float* __restrict__ Wr0,
                               const float* __restrict__ Wl, const float* __restrict__ Wr,
                               bf16x8* __restrict__ frag0, bf16x8* __restrict__ frag1,
                               size_t fragstride) {
    int t = blockIdx.x * 256 + threadIdx.x;
    const int L0 = 4 * 40 * 64, LN = 10 * 40 * 64;
    if (t < L0) {
        bfrag_one(Wl0, Wr0, frag0, D0, t);
    } else {
        int u = t - L0;
        int layer = u / LN;
        if (layer >= 4) return;
        bfrag_one(Wl + (size_t)layer * WDIM * WDIM, Wr + (size_t)layer * WDIM * WDIM,
                  frag1 + layer * fragstride, WDIM, u - layer * LN);
    }
}

// ---------------- MFMA dual GEMM: xl(bf16 padded) | xr(f32) = A @ [Bl|Br] + b --
// split-bf16 hi/lo, 3 cross-product MFMAs, f32 accumulate.
// use_map: A-row indirection (layer-0 embedding fold-in).
__global__ __launch_bounds__(256) void gemm_mfma(
    const float* __restrict__ A, const int* __restrict__ xmap, int use_map,
    const bf16x8* __restrict__ Bfrag,
    const float* __restrict__ bl, const float* __restrict__ br,
    ushort* __restrict__ Cl16, float* __restrict__ Cr,
    int M, int K, int ksteps) {

    __shared__ bf16x8 Alds[8][2][64];
    __shared__ bf16x8 Blds[8][2][64];

    int id = blockIdx.x;
    int mb = (id & 7) + 8 * (id / 40);
    int cb = (id >> 3) % 5;
    if (mb >= 235) return;

    int tid  = threadIdx.x;
    int lane = tid & 63;
    int wid  = tid >> 6;
    int wm = wid >> 1, wn = wid & 1;
    int row0 = mb * 128;

    f32x4 acc[4][4] = {};

    for (int s = 0; s < ksteps; s++) {
        int kt = s * 32;
        #pragma unroll
        for (int u0 = 0; u0 < 2; u0++) {
            int u = u0 * 256 + tid;
            int m16  = u >> 6;
            int slot = u & 63;
            int kh = slot >> 4, rl = slot & 15;
            int gr = row0 + m16 * 16 + rl;
            int gc = kt + kh * 8;
            float4 v0 = make_float4(0.f,0.f,0.f,0.f), v1 = v0;
            if (gr < M) {
                int ar = use_map ? xmap[gr] : gr;
                const float* ap = A + (size_t)ar * K + gc;
                if (gc + 4 <= K) v0 = *(const float4*)ap;
                if (gc + 8 <= K) v1 = *(const float4*)(ap + 4);
            }
            union { bf16x8 v; __bf16 e[8]; } hi, lo;
            const float* xs0 = (const float*)&v0;
            const float* xs1 = (const float*)&v1;
            #pragma unroll
            for (int j = 0; j < 8; j++) {
                float x = (j < 4) ? xs0[j] : xs1[j - 4];
                __bf16 h = (__bf16)x;
                hi.e[j] = h;
                lo.e[j] = (__bf16)(x - (float)h);
            }
            Alds[m16][0][slot] = hi.v;
            Alds[m16][1][slot] = lo.v;
        }
        {
            const float4* bsrc = (const float4*)(Bfrag + ((size_t)(s * 40 + cb * 8) * 2) * 64);
            float4* bdst = (float4*)&Blds[0][0][0];
            #pragma unroll
            for (int c = 0; c < 4; c++)
                bdst[c * 256 + tid] = bsrc[c * 256 + tid];
        }
        __syncthreads();

        bf16x8 af[4][2], bfr[4][2];
        #pragma unroll
        for (int m = 0; m < 4; m++) {
            af[m][0] = Alds[wm * 4 + m][0][lane];
            af[m][1] = Alds[wm * 4 + m][1][lane];
        }
        #pragma unroll
        for (int n = 0; n < 4; n++) {
            bfr[n][0] = Blds[wn * 4 + n][0][lane];
            bfr[n][1] = Blds[wn * 4 + n][1][lane];
        }
        #pragma unroll
        for (int m = 0; m < 4; m++)
            #pragma unroll
            for (int n = 0; n < 4; n++) {
                acc[m][n] = __builtin_amdgcn_mfma_f32_16x16x32_bf16(af[m][1], bfr[n][0], acc[m][n], 0, 0, 0);
                acc[m][n] = __builtin_amdgcn_mfma_f32_16x16x32_bf16(af[m][0], bfr[n][1], acc[m][n], 0, 0, 0);
                acc[m][n] = __builtin_amdgcn_mfma_f32_16x16x32_bf16(af[m][0], bfr[n][0], acc[m][n], 0, 0, 0);
            }
        __syncthreads();
    }

    int r0 = row0 + wm * 64;
    int c0 = cb * 128 + wn * 64;
    #pragma unroll
    for (int m = 0; m < 4; m++)
        #pragma unroll
        for (int n = 0; n < 4; n++) {
            #pragma unroll
            for (int reg = 0; reg < 4; reg++) {
                int gr = r0 + m * 16 + (lane >> 4) * 4 + reg;
                int gc = c0 + n * 16 + (lane & 15);
                if (gr < M && gc < NW) {
                    if (gc < WDIM) {
                        float v = acc[m][n][reg] + bl[gc];
                        __bf16 b = (__bf16)v;
                        Cl16[(size_t)gr * XLP + gc] = *(ushort*)&b;
                    } else {
                        int cc = gc - WDIM;
                        Cr[(size_t)gr * WDIM + cc] = acc[m][n][reg] + br[cc];
                    }
                }
            }
        }
}

// ---------------- fused GAT: 2 waves per node, 2-edge ILP, bf16 xl gather ----
// Block = 4 waves = 2 nodes. Wave sub∈{0,1} handles half the node's edges.
// Softmax state packed by lane residue r=lane&3 (r=0:h0 r=1:h1 r=2:h2).
__global__ __launch_bounds__(256) void gat_edge_agg(
    const ushort* __restrict__ xl, const float* __restrict__ xr,
    const int* __restrict__ offsets, const int* __restrict__ csr_src,
    const float* __restrict__ att, const float* __restrict__ bias,
    float* __restrict__ fout) {
    __shared__ float st[4][64][8];
    int wid  = threadIdx.x >> 6;
    int lane = threadIdx.x & 63;
    int node = blockIdx.x * 2 + (wid >> 1);   // NODES even: always valid
    int sub  = wid & 1;
    int r = lane & 3;
    bool c0 = lane < 50;   // j0: head0 else head1
    bool c1 = lane < 36;   // j1: head1 else head2

    float2 aw2[3], xr2[3];
    const float2* xrrow = (const float2*)(xr + (size_t)node * WDIM);
    #pragma unroll
    for (int j = 0; j < 3; j++) {
        int i = lane + 64 * j;
        if (i < 150) {
            aw2[j].x = att[2 * i]; aw2[j].y = att[2 * i + 1];
            xr2[j] = xrrow[i];
        } else {
            aw2[j].x = 0.f; aw2[j].y = 0.f;
            xr2[j].x = 0.f; xr2[j].y = 0.f;
        }
    }

    float mq = -1e38f, sq = 0.f;
    float2 acc2[3] = {};

    int beg = offsets[node], end = offsets[node + 1];
    int half = (end - beg + 1) >> 1;
    int lo = beg + sub * half;
    int hi = sub ? end : beg + half;

    for (int i = lo; i < hi; i += 2) {
        bool act_b = (i + 1) < hi;
        int sa = csr_src[i];
        int sb = csr_src[act_b ? i + 1 : i];
        const ushort* ra = xl + (size_t)sa * XLP;
        const ushort* rb = xl + (size_t)sb * XLP;
        ushort2 ua[3], ub[3];
        ua[0] = *(const ushort2*)(ra + 2 * lane);
        ub[0] = *(const ushort2*)(rb + 2 * lane);
        ua[1] = *(const ushort2*)(ra + 2 * (lane + 64));
        ub[1] = *(const ushort2*)(rb + 2 * (lane + 64));
        if (lane < 32) {
            ua[2] = *(const ushort2*)(ra + 2 * (lane + 128));
            ub[2] = *(const ushort2*)(rb + 2 * (lane + 128));
        } else { ua[2].x = ua[2].y = ub[2].x = ub[2].y = 0; }

        float2 va[3], vb[3];
        #pragma unroll
        for (int j = 0; j < 3; j++) {
            va[j].x = __uint_as_float(((unsigned)ua[j].x) << 16);
            va[j].y = __uint_as_float(((unsigned)ua[j].y) << 16);
            vb[j].x = __uint_as_float(((unsigned)ub[j].x) << 16);
            vb[j].y = __uint_as_float(((unsigned)ub[j].y) << 16);
        }

        float qa[3], qb[3];
        #pragma unroll
        for (int j = 0; j < 3; j++) {
            float tax = va[j].x + xr2[j].x; tax = fmaxf(tax, NEG * tax);
            float tay = va[j].y + xr2[j].y; tay = fmaxf(tay, NEG * tay);
            float tbx = vb[j].x + xr2[j].x; tbx = fmaxf(tbx, NEG * tbx);
            float tby = vb[j].y + xr2[j].y; tby = fmaxf(tby, NEG * tby);
            qa[j] = tax * aw2[j].x + tay * aw2[j].y;
            qb[j] = tbx * aw2[j].x + tby * aw2[j].y;
        }
        float pa0 = c0 ? qa[0] : 0.f;
        float pa1 = (c0 ? 0.f : qa[0]) + (c1 ? qa[1] : 0.f);
        float pa2 = (c1 ? 0.f : qa[1]) + qa[2];
        float pb0 = c0 ? qb[0] : 0.f;
        float pb1 = (c0 ? 0.f : qb[0]) + (c1 ? qb[1] : 0.f);
        float pb2 = (c1 ? 0.f : qb[1]) + qb[2];

        pa0 += __shfl_xor(pa0, 1, 64); pa1 += __shfl_xor(pa1, 1, 64); pa2 += __shfl_xor(pa2, 1, 64);
        pb0 += __shfl_xor(pb0, 1, 64); pb1 += __shfl_xor(pb1, 1, 64); pb2 += __shfl_xor(pb2, 1, 64);
        pa0 += __shfl_xor(pa0, 2, 64); pa1 += __shfl_xor(pa1, 2, 64); pa2 += __shfl_xor(pa2, 2, 64);
        pb0 += __shfl_xor(pb0, 2, 64); pb1 += __shfl_xor(pb1, 2, 64); pb2 += __shfl_xor(pb2, 2, 64);
        float sqa = (r == 1) ? pa1 : ((r == 2) ? pa2 : pa0);
        float sqb = (r == 1) ? pb1 : ((r == 2) ? pb2 : pb0);
        sqa += __shfl_xor(sqa, 4, 64);  sqb += __shfl_xor(sqb, 4, 64);
        sqa += __shfl_xor(sqa, 8, 64);  sqb += __shfl_xor(sqb, 8, 64);
        sqa += __shfl_xor(sqa, 16, 64); sqb += __shfl_xor(sqb, 16, 64);
        sqa += __shfl_xor(sqa, 32, 64); sqb += __shfl_xor(sqb, 32, 64);
        if (!act_b) sqb = -3e38f;

        float hiq = fmaxf(sqa, sqb);
        if (__any(hiq > mq + 8.f)) {
            float nmq = fmaxf(mq, hiq);
            float eq = __expf(mq - nmq);
            sq *= eq;
            float e0 = __shfl(eq, 0, 64), e1 = __shfl(eq, 1, 64), e2 = __shfl(eq, 2, 64);
            float ej0 = c0 ? e0 : e1, ej1 = c1 ? e1 : e2;
            acc2[0].x *= ej0; acc2[0].y *= ej0;
            acc2[1].x *= ej1; acc2[1].y *= ej1;
            acc2[2].x *= e2;  acc2[2].y *= e2;
            mq = nmq;
        }
        float cqa = __expf(sqa - mq), cqb = __expf(sqb - mq);
        sq += cqa + cqb;
        float ca0 = __shfl(cqa, 0, 64), ca1 = __shfl(cqa, 1, 64), ca2 = __shfl(cqa, 2, 64);
        float cb0 = __shfl(cqb, 0, 64), cb1 = __shfl(cqb, 1, 64), cb2 = __shfl(cqb, 2, 64);
        float caj[3] = { c0 ? ca0 : ca1, c1 ? ca1 : ca2, ca2 };
        float cbj[3] = { c0 ? cb0 : cb1, c1 ? cb1 : cb2, cb2 };
        #pragma unroll
        for (int j = 0; j < 3; j++) {
            acc2[j].x = fmaf(caj[j], va[j].x, acc2[j].x);
            acc2[j].y = fmaf(caj[j], va[j].y, acc2[j].y);
            acc2[j].x = fmaf(cbj[j], vb[j].x, acc2[j].x);
            acc2[j].y = fmaf(cbj[j], vb[j].y, acc2[j].y);
        }
    }

    // publish partial state
    st[wid][lane][0] = mq;
    st[wid][lane][1] = sq;
    st[wid][lane][2] = acc2[0].x; st[wid][lane][3] = acc2[0].y;
    st[wid][lane][4] = acc2[1].x; st[wid][lane][5] = acc2[1].y;
    st[wid][lane][6] = acc2[2].x; st[wid][lane][7] = acc2[2].y;
    __syncthreads();
    if (sub) return;

    // exact merge with partner wave
    float m1 = st[wid ^ 1][lane][0];
    float s1 = st[wid ^ 1][lane][1];
    float2 o1[3];
    o1[0].x = st[wid ^ 1][lane][2]; o1[0].y = st[wid ^ 1][lane][3];
    o1[1].x = st[wid ^ 1][lane][4]; o1[1].y = st[wid ^ 1][lane][5];
    o1[2].x = st[wid ^ 1][lane][6]; o1[2].y = st[wid ^ 1][lane][7];

    float M  = fmaxf(mq, m1);
    float ea = __expf(mq - M), eb = __expf(m1 - M);
    float sF = sq * ea + s1 * eb;
    float iq = 1.f / sF;
    float ea0 = __shfl(ea, 0, 64), ea1 = __shfl(ea, 1, 64), ea2 = __shfl(ea, 2, 64);
    float eb0 = __shfl(eb, 0, 64), eb1 = __shfl(eb, 1, 64), eb2 = __shfl(eb, 2, 64);
    float i0  = __shfl(iq, 0, 64), i1  = __shfl(iq, 1, 64), i2  = __shfl(iq, 2, 64);
    float eaj[3]  = { c0 ? ea0 : ea1, c1 ? ea1 : ea2, ea2 };
    float ebj[3]  = { c0 ? eb0 : eb1, c1 ? eb1 : eb2, eb2 };
    float isel[3] = { c0 ? i0 : i1,  c1 ? i1 : i2,  i2 };

    #pragma unroll
    for (int j = 0; j < 3; j++) {
        int fi = lane + 64 * j;
        if (fi < 150) {
            float ax = acc2[j].x * eaj[j] + o1[j].x * ebj[j];
            float ay = acc2[j].y * eaj[j] + o1[j].y * ebj[j];
            float2 o;
            o.x = fmaxf(ax * isel[j] + bias[2 * fi],     0.f);
            o.y = fmaxf(ay * isel[j] + bias[2 * fi + 1], 0.f);
            *(float2*)(fout + (size_t)node * WDIM + 2 * fi) = o;
        }
    }
}

// ---------------- host ----------------
static inline size_t align256(size_t x) { return (x + 255) & ~(size_t)255; }

extern "C" void kernel_launch(void* const* d_in, const int* in_sizes, int n_in,
                              void* d_out, int out_size, void* d_ws, size_t ws_size,
                              hipStream_t stream) {
    const int*   x     = (const int*)d_in[0];
    const int*   ei    = (const int*)d_in[1];
    const float* emb   = (const float*)d_in[2];
    const float* Wl0   = (const float*)d_in[3];
    const float* bl0   = (const float*)d_in[4];
    const float* Wr0   = (const float*)d_in[5];
    const float* br0   = (const float*)d_in[6];
    const float* att0  = (const float*)d_in[7];
    const float* bias0 = (const float*)d_in[8];
    const float* Wl    = (const float*)d_in[9];
    const float* bl    = (const float*)d_in[10];
    const float* Wr    = (const float*)d_in[11];
    const float* br    = (const float*)d_in[12];
    const float* att   = (const float*)d_in[13];
    const float* bias  = (const float*)d_in[14];

    char* ws = (char*)d_ws;
    size_t off = 0;
    float* h      = (float*)(ws + off);  off = align256(off + (size_t)NODES * WDIM * 4);
    ushort* xlb16 = (ushort*)(ws + off); off = align256(off + (size_t)NODES * XLP * 2);
    float* xrb    = (float*)(ws + off);  off = align256(off + (size_t)NODES * WDIM * 4);
    int* counts   = (int*)(ws + off);    off = align256(off + (size_t)NODES * 4);
    int* cursor   = (int*)(ws + off);    off = align256(off + (size_t)NODES * 4);
    int* offsets  = (int*)(ws + off);    off = align256(off + (size_t)(NODES + 1) * 4);
    int* csr_src  = (int*)(ws + off);    off = align256(off + (size_t)ETOT * 4);
    size_t frag_l0_elems = (size_t)4 * 40 * 2 * 64;    // bf16x8 units
    size_t frag_ln_elems = (size_t)10 * 40 * 2 * 64;
    bf16x8* bfrag0 = (bf16x8*)(ws + off); off = align256(off + frag_l0_elems * 16);
    bf16x8* bfrag1 = (bf16x8*)(ws + off); off = align256(off + 4 * frag_ln_elems * 16);

    float* out = (float*)d_out;

    // all weight fragment pre-splits in ONE launch
    {
        int total = 4 * 40 * 64 + 4 * 10 * 40 * 64;
        make_bfrag_all<<<(total + 255) / 256, 256, 0, stream>>>(
            Wl0, Wr0, Wl, Wr, bfrag0, bfrag1, frag_ln_elems);
    }

    // zero xl (pads stay zero forever; gemm writes only cols<300)
    hipMemsetAsync(xlb16, 0, (size_t)NODES * XLP * 2, stream);

    // CSR build
    hipMemsetAsync(counts, 0, (size_t)NODES * 4, stream);
    hipMemsetAsync(cursor, 0, (size_t)NODES * 4, stream);
    count_edges<<<(ETOT + 255) / 256, 256, 0, stream>>>(ei, counts);
    scan_kernel<<<1, 1024, 0, stream>>>(counts, offsets, NODES);
    scatter_edges<<<(ETOT + 255) / 256, 256, 0, stream>>>(ei, offsets, cursor, csr_src);

    int agg_blocks = NODES / 2;   // 2 nodes per block (NODES even)

    // layer 0: A = emb with row indirection
    gemm_mfma<<<1200, 256, 0, stream>>>(emb, x, 1, bfrag0, bl0, br0, xlb16, xrb, NODES, D0, 4);
    gat_edge_agg<<<agg_blocks, 256, 0, stream>>>(xlb16, xrb, offsets, csr_src, att0, bias0, h);

    // layers 1..4
    for (int i = 0; i < 4; i++) {
        float* dst = (i == 3) ? out : h;
        gemm_mfma<<<1200, 256, 0, stream>>>(h, nullptr, 0, bfrag1 + i * frag_ln_elems,
                                            bl + i * WDIM, br + i * WDIM,
                                            xlb16, xrb, NODES, WDIM, 10);
        gat_edge_agg<<<agg_blocks, 256, 0, stream>>>(xlb16, xrb, offsets, csr_src,
                                                     att + (size_t)i * WDIM,
                                                     bias + (size_t)i * WDIM, dst);
    }
}

// Round 13
// 810.503 us; speedup vs baseline: 1.1469x; 1.0505x over previous
//
#include <hip/hip_runtime.h>

#define NODES   30000
#define E0N     480000
#define ETOT    510000   // E0N + NODES self loops
#define D0      100
#define WDIM    300      // H*F = 3*100
#define NW      600      // dual output width
#define NEG     0.2f
#define XLP     384      // head-major padded xl row: 3 heads x 128 (bf16 elems)

typedef __bf16 bf16x8 __attribute__((ext_vector_type(8)));
typedef float  f32x4  __attribute__((ext_vector_type(4)));

// ---------------- CSR build ----------------
__global__ void count_edges(const int* __restrict__ ei, int* __restrict__ counts) {
    int e = blockIdx.x * 256 + threadIdx.x;
    if (e >= ETOT) return;
    int d = (e < E0N) ? ei[E0N + e] : (e - E0N);
    atomicAdd(&counts[d], 1);
}

__global__ __launch_bounds__(1024) void scan_kernel(const int* __restrict__ counts,
                                                    int* __restrict__ offsets, int n) {
    __shared__ int lds[1024];
    const int CH = 32;
    int t = threadIdx.x;
    int base = t * CH;
    int loc[CH];
    int sum = 0;
    #pragma unroll
    for (int i = 0; i < CH; i++) {
        int v = (base + i < n) ? counts[base + i] : 0;
        loc[i] = sum;
        sum += v;
    }
    lds[t] = sum;
    __syncthreads();
    for (int off = 1; off < 1024; off <<= 1) {
        int v = (t >= off) ? lds[t - off] : 0;
        __syncthreads();
        lds[t] += v;
        __syncthreads();
    }
    int ex = (t == 0) ? 0 : lds[t - 1];
    #pragma unroll
    for (int i = 0; i < CH; i++) {
        int idx = base + i;
        if (idx < n) offsets[idx] = ex + loc[i];
    }
    if (t == 0) offsets[n] = lds[1023];
}

__global__ void scatter_edges(const int* __restrict__ ei, const int* __restrict__ offsets,
                              int* __restrict__ cursor, int* __restrict__ csr_src) {
    int e = blockIdx.x * 256 + threadIdx.x;
    if (e >= ETOT) return;
    int s, d;
    if (e < E0N) { s = ei[e]; d = ei[E0N + e]; }
    else         { s = e - E0N; d = s; }
    int pos = offsets[d] + atomicAdd(&cursor[d], 1);
    csr_src[pos] = s;
}

// ---------------- all-layer B fragment pre-split (one launch) ----------------
__device__ __forceinline__ void bfrag_one(const float* Bl, const float* Br,
                                          bf16x8* out, int K, int t) {
    int lane = t & 63;
    int n16  = (t >> 6) % 40;
    int s    = t / (64 * 40);
    int c = n16 * 16 + (lane & 15);
    union { bf16x8 v; __bf16 e[8]; } hi, lo;
    #pragma unroll
    for (int j = 0; j < 8; j++) {
        int k = s * 32 + ((lane >> 4) * 8) + j;
        float x = 0.f;
        if (k < K && c < NW)
            x = (c < WDIM) ? Bl[(size_t)k * WDIM + c] : Br[(size_t)k * WDIM + c - WDIM];
        __bf16 h = (__bf16)x;
        hi.e[j] = h;
        lo.e[j] = (__bf16)(x - (float)h);
    }
    size_t base = ((size_t)(s * 40 + n16) * 2) * 64 + lane;
    out[base]      = hi.v;
    out[base + 64] = lo.v;
}

__global__ void make_bfrag_all(const float* __restrict__ Wl0, const float* __restrict__ Wr0,
                               const float* __restrict__ Wl, const float* __restrict__ Wr,
                               bf16x8* __restrict__ frag0, bf16x8* __restrict__ frag1,
                               size_t fragstride) {
    int t = blockIdx.x * 256 + threadIdx.x;
    const int L0 = 4 * 40 * 64, LN = 10 * 40 * 64;
    if (t < L0) {
        bfrag_one(Wl0, Wr0, frag0, D0, t);
    } else {
        int u = t - L0;
        int layer = u / LN;
        if (layer >= 4) return;
        bfrag_one(Wl + (size_t)layer * WDIM * WDIM, Wr + (size_t)layer * WDIM * WDIM,
                  frag1 + layer * fragstride, WDIM, u - layer * LN);
    }
}

// ---------------- MFMA dual GEMM: xl(bf16 head-major) | xr(f32) = A@[Bl|Br]+b --
// split-bf16 hi/lo, 3 cross-product MFMAs, f32 accumulate.
// B fragments load global->registers directly (fragment-linear, L2-resident).
__global__ __launch_bounds__(256) void gemm_mfma(
    const float* __restrict__ A, const int* __restrict__ xmap, int use_map,
    const bf16x8* __restrict__ Bfrag,
    const float* __restrict__ bl, const float* __restrict__ br,
    ushort* __restrict__ Cl16, float* __restrict__ Cr,
    int M, int K, int ksteps) {

    __shared__ bf16x8 Alds[8][2][64];

    int id = blockIdx.x;
    int mb = (id & 7) + 8 * (id / 40);
    int cb = (id >> 3) % 5;
    if (mb >= 235) return;

    int tid  = threadIdx.x;
    int lane = tid & 63;
    int wid  = tid >> 6;
    int wm = wid >> 1, wn = wid & 1;
    int row0 = mb * 128;

    f32x4 acc[4][4] = {};

    for (int s = 0; s < ksteps; s++) {
        int kt = s * 32;
        #pragma unroll
        for (int u0 = 0; u0 < 2; u0++) {
            int u = u0 * 256 + tid;
            int m16  = u >> 6;
            int slot = u & 63;
            int kh = slot >> 4, rl = slot & 15;
            int gr = row0 + m16 * 16 + rl;
            int gc = kt + kh * 8;
            float4 v0 = make_float4(0.f,0.f,0.f,0.f), v1 = v0;
            if (gr < M) {
                int ar = use_map ? xmap[gr] : gr;
                const float* ap = A + (size_t)ar * K + gc;
                if (gc + 4 <= K) v0 = *(const float4*)ap;
                if (gc + 8 <= K) v1 = *(const float4*)(ap + 4);
            }
            union { bf16x8 v; __bf16 e[8]; } hi, lo;
            const float* xs0 = (const float*)&v0;
            const float* xs1 = (const float*)&v1;
            #pragma unroll
            for (int j = 0; j < 8; j++) {
                float x = (j < 4) ? xs0[j] : xs1[j - 4];
                __bf16 h = (__bf16)x;
                hi.e[j] = h;
                lo.e[j] = (__bf16)(x - (float)h);
            }
            Alds[m16][0][slot] = hi.v;
            Alds[m16][1][slot] = lo.v;
        }
        // B fragments: direct global->reg (coalesced 1KB per load, L2-hot)
        bf16x8 bfr[4][2];
        {
            const bf16x8* bwave = Bfrag + ((size_t)(s * 40 + cb * 8 + wn * 4) * 2) * 64;
            #pragma unroll
            for (int n = 0; n < 4; n++) {
                bfr[n][0] = bwave[(n * 2 + 0) * 64 + lane];
                bfr[n][1] = bwave[(n * 2 + 1) * 64 + lane];
            }
        }
        __syncthreads();

        bf16x8 af[4][2];
        #pragma unroll
        for (int m = 0; m < 4; m++) {
            af[m][0] = Alds[wm * 4 + m][0][lane];
            af[m][1] = Alds[wm * 4 + m][1][lane];
        }
        #pragma unroll
        for (int m = 0; m < 4; m++)
            #pragma unroll
            for (int n = 0; n < 4; n++) {
                acc[m][n] = __builtin_amdgcn_mfma_f32_16x16x32_bf16(af[m][1], bfr[n][0], acc[m][n], 0, 0, 0);
                acc[m][n] = __builtin_amdgcn_mfma_f32_16x16x32_bf16(af[m][0], bfr[n][1], acc[m][n], 0, 0, 0);
                acc[m][n] = __builtin_amdgcn_mfma_f32_16x16x32_bf16(af[m][0], bfr[n][0], acc[m][n], 0, 0, 0);
            }
        __syncthreads();
    }

    int r0 = row0 + wm * 64;
    int c0 = cb * 128 + wn * 64;
    #pragma unroll
    for (int m = 0; m < 4; m++)
        #pragma unroll
        for (int n = 0; n < 4; n++) {
            #pragma unroll
            for (int reg = 0; reg < 4; reg++) {
                int gr = r0 + m * 16 + (lane >> 4) * 4 + reg;
                int gc = c0 + n * 16 + (lane & 15);
                if (gr < M && gc < NW) {
                    if (gc < WDIM) {
                        float v = acc[m][n][reg] + bl[gc];
                        int head = gc / 100;
                        int fh = gc - head * 100;
                        __bf16 b = (__bf16)v;
                        Cl16[(size_t)gr * XLP + head * 128 + fh] = *(ushort*)&b;
                    } else {
                        int cc = gc - WDIM;
                        Cr[(size_t)gr * WDIM + cc] = acc[m][n][reg] + br[cc];
                    }
                }
            }
        }
}

// ---------------- fused GAT: head-uniform lanes, 2 waves/node, 2-edge ILP ----
// xl head-major [h0*128|h1*128|h2*128] bf16. Quad part: lane covers elems
// 4*(lane&31)..+3 of head (lane>>5) in {0,1}; pair part: elems 2*lane of head2.
// Softmax state per lane: (m_h,s_h) for its quad head, (m_2,s_2) for head2.
__global__ __launch_bounds__(256) void gat_edge_agg(
    const ushort* __restrict__ xl, const float* __restrict__ xr,
    const int* __restrict__ offsets, const int* __restrict__ csr_src,
    const float* __restrict__ att, const float* __restrict__ bias,
    float* __restrict__ fout) {
    __shared__ float st[4][64][10];
    int wid  = threadIdx.x >> 6;
    int lane = threadIdx.x & 63;
    int node = blockIdx.x * 2 + (wid >> 1);   // NODES even: always valid
    int sub  = wid & 1;
    int lq    = lane & 31;
    int headq = lane >> 5;   // 0 or 1

    float aw4[4] = {}, xr4[4] = {}, awp[2] = {}, xrp[2] = {};
    if (lq < 25) {
        float4 a = *(const float4*)(att + headq * 100 + 4 * lq);
        float4 b = *(const float4*)(xr + (size_t)node * WDIM + headq * 100 + 4 * lq);
        aw4[0] = a.x; aw4[1] = a.y; aw4[2] = a.z; aw4[3] = a.w;
        xr4[0] = b.x; xr4[1] = b.y; xr4[2] = b.z; xr4[3] = b.w;
    }
    if (lane < 50) {
        float2 a = *(const float2*)(att + 200 + 2 * lane);
        float2 b = *(const float2*)(xr + (size_t)node * WDIM + 200 + 2 * lane);
        awp[0] = a.x; awp[1] = a.y;
        xrp[0] = b.x; xrp[1] = b.y;
    }

    float m_h = -1e38f, s_h = 0.f, m_2 = -1e38f, s_2 = 0.f;
    float acc4[4] = {}, acc2[2] = {};

    int beg = offsets[node], end = offsets[node + 1];
    int half = (end - beg + 1) >> 1;
    int lo = beg + sub * half;
    int hi = sub ? end : beg + half;

    for (int i = lo; i < hi; i += 2) {
        bool act_b = (i + 1) < hi;
        int sa = csr_src[i];
        int sb = csr_src[act_b ? i + 1 : i];
        const ushort* ra = xl + (size_t)sa * XLP;
        const ushort* rb = xl + (size_t)sb * XLP;
        ushort4 a4 = *(const ushort4*)(ra + 4 * lane);
        ushort4 b4 = *(const ushort4*)(rb + 4 * lane);
        ushort2 a2 = *(const ushort2*)(ra + 256 + 2 * lane);
        ushort2 b2 = *(const ushort2*)(rb + 256 + 2 * lane);

        float va4[4], vb4[4], va2[2], vb2[2];
        va4[0] = __uint_as_float(((unsigned)a4.x) << 16);
        va4[1] = __uint_as_float(((unsigned)a4.y) << 16);
        va4[2] = __uint_as_float(((unsigned)a4.z) << 16);
        va4[3] = __uint_as_float(((unsigned)a4.w) << 16);
        vb4[0] = __uint_as_float(((unsigned)b4.x) << 16);
        vb4[1] = __uint_as_float(((unsigned)b4.y) << 16);
        vb4[2] = __uint_as_float(((unsigned)b4.z) << 16);
        vb4[3] = __uint_as_float(((unsigned)b4.w) << 16);
        va2[0] = __uint_as_float(((unsigned)a2.x) << 16);
        va2[1] = __uint_as_float(((unsigned)a2.y) << 16);
        vb2[0] = __uint_as_float(((unsigned)b2.x) << 16);
        vb2[1] = __uint_as_float(((unsigned)b2.y) << 16);

        float qA = 0.f, qB = 0.f, qA2 = 0.f, qB2 = 0.f;
        #pragma unroll
        for (int k = 0; k < 4; k++) {
            float ta = va4[k] + xr4[k]; ta = fmaxf(ta, NEG * ta);
            float tb = vb4[k] + xr4[k]; tb = fmaxf(tb, NEG * tb);
            qA = fmaf(ta, aw4[k], qA);
            qB = fmaf(tb, aw4[k], qB);
        }
        #pragma unroll
        for (int k = 0; k < 2; k++) {
            float ta = va2[k] + xrp[k]; ta = fmaxf(ta, NEG * ta);
            float tb = vb2[k] + xrp[k]; tb = fmaxf(tb, NEG * tb);
            qA2 = fmaf(ta, awp[k], qA2);
            qB2 = fmaf(tb, awp[k], qB2);
        }
        // quad: reduce within 32-lane half (head-uniform)
        qA += __shfl_xor(qA, 1, 64);  qB += __shfl_xor(qB, 1, 64);
        qA += __shfl_xor(qA, 2, 64);  qB += __shfl_xor(qB, 2, 64);
        qA += __shfl_xor(qA, 4, 64);  qB += __shfl_xor(qB, 4, 64);
        qA += __shfl_xor(qA, 8, 64);  qB += __shfl_xor(qB, 8, 64);
        qA += __shfl_xor(qA, 16, 64); qB += __shfl_xor(qB, 16, 64);
        // pair: full-wave reduce (head2)
        qA2 += __shfl_xor(qA2, 1, 64);  qB2 += __shfl_xor(qB2, 1, 64);
        qA2 += __shfl_xor(qA2, 2, 64);  qB2 += __shfl_xor(qB2, 2, 64);
        qA2 += __shfl_xor(qA2, 4, 64);  qB2 += __shfl_xor(qB2, 4, 64);
        qA2 += __shfl_xor(qA2, 8, 64);  qB2 += __shfl_xor(qB2, 8, 64);
        qA2 += __shfl_xor(qA2, 16, 64); qB2 += __shfl_xor(qB2, 16, 64);
        qA2 += __shfl_xor(qA2, 32, 64); qB2 += __shfl_xor(qB2, 32, 64);
        if (!act_b) { qB = -3e38f; qB2 = -3e38f; }

        // defer-rescale (THR=8), lane-local state
        float hi_h = fmaxf(qA, qB), hi_2 = fmaxf(qA2, qB2);
        if (__any(hi_h > m_h + 8.f || hi_2 > m_2 + 8.f)) {
            float nm_h = fmaxf(m_h, hi_h), nm_2 = fmaxf(m_2, hi_2);
            float e_h = __expf(m_h - nm_h), e_2 = __expf(m_2 - nm_2);
            s_h *= e_h; s_2 *= e_2;
            #pragma unroll
            for (int k = 0; k < 4; k++) acc4[k] *= e_h;
            acc2[0] *= e_2; acc2[1] *= e_2;
            m_h = nm_h; m_2 = nm_2;
        }
        float cA  = __expf(qA - m_h),  cB  = __expf(qB - m_h);
        float cA2 = __expf(qA2 - m_2), cB2 = __expf(qB2 - m_2);
        s_h += cA + cB; s_2 += cA2 + cB2;
        #pragma unroll
        for (int k = 0; k < 4; k++) {
            acc4[k] = fmaf(cA, va4[k], acc4[k]);
            acc4[k] = fmaf(cB, vb4[k], acc4[k]);
        }
        #pragma unroll
        for (int k = 0; k < 2; k++) {
            acc2[k] = fmaf(cA2, va2[k], acc2[k]);
            acc2[k] = fmaf(cB2, vb2[k], acc2[k]);
        }
    }

    // publish partial state
    st[wid][lane][0] = m_h; st[wid][lane][1] = s_h;
    st[wid][lane][2] = m_2; st[wid][lane][3] = s_2;
    st[wid][lane][4] = acc4[0]; st[wid][lane][5] = acc4[1];
    st[wid][lane][6] = acc4[2]; st[wid][lane][7] = acc4[3];
    st[wid][lane][8] = acc2[0]; st[wid][lane][9] = acc2[1];
    __syncthreads();
    if (sub) return;

    // exact merge with partner wave (lane-local, no shuffles)
    const float* p = st[wid ^ 1][lane];
    float pm_h = p[0], ps_h = p[1], pm_2 = p[2], ps_2 = p[3];

    float M_h = fmaxf(m_h, pm_h);
    float ea_h = __expf(m_h - M_h), eb_h = __expf(pm_h - M_h);
    float inv_h = 1.f / (s_h * ea_h + ps_h * eb_h);
    float M_2 = fmaxf(m_2, pm_2);
    float ea_2 = __expf(m_2 - M_2), eb_2 = __expf(pm_2 - M_2);
    float inv_2 = 1.f / (s_2 * ea_2 + ps_2 * eb_2);

    if (lq < 25) {
        float4 bv = *(const float4*)(bias + headq * 100 + 4 * lq);
        float4 o;
        o.x = fmaxf((acc4[0] * ea_h + p[4] * eb_h) * inv_h + bv.x, 0.f);
        o.y = fmaxf((acc4[1] * ea_h + p[5] * eb_h) * inv_h + bv.y, 0.f);
        o.z = fmaxf((acc4[2] * ea_h + p[6] * eb_h) * inv_h + bv.z, 0.f);
        o.w = fmaxf((acc4[3] * ea_h + p[7] * eb_h) * inv_h + bv.w, 0.f);
        *(float4*)(fout + (size_t)node * WDIM + headq * 100 + 4 * lq) = o;
    }
    if (lane < 50) {
        float2 bv = *(const float2*)(bias + 200 + 2 * lane);
        float2 o;
        o.x = fmaxf((acc2[0] * ea_2 + p[8] * eb_2) * inv_2 + bv.x, 0.f);
        o.y = fmaxf((acc2[1] * ea_2 + p[9] * eb_2) * inv_2 + bv.y, 0.f);
        *(float2*)(fout + (size_t)node * WDIM + 200 + 2 * lane) = o;
    }
}

// ---------------- host ----------------
static inline size_t align256(size_t x) { return (x + 255) & ~(size_t)255; }

extern "C" void kernel_launch(void* const* d_in, const int* in_sizes, int n_in,
                              void* d_out, int out_size, void* d_ws, size_t ws_size,
                              hipStream_t stream) {
    const int*   x     = (const int*)d_in[0];
    const int*   ei    = (const int*)d_in[1];
    const float* emb   = (const float*)d_in[2];
    const float* Wl0   = (const float*)d_in[3];
    const float* bl0   = (const float*)d_in[4];
    const float* Wr0   = (const float*)d_in[5];
    const float* br0   = (const float*)d_in[6];
    const float* att0  = (const float*)d_in[7];
    const float* bias0 = (const float*)d_in[8];
    const float* Wl    = (const float*)d_in[9];
    const float* bl    = (const float*)d_in[10];
    const float* Wr    = (const float*)d_in[11];
    const float* br    = (const float*)d_in[12];
    const float* att   = (const float*)d_in[13];
    const float* bias  = (const float*)d_in[14];

    char* ws = (char*)d_ws;
    size_t off = 0;
    float* h      = (float*)(ws + off);  off = align256(off + (size_t)NODES * WDIM * 4);
    ushort* xlb16 = (ushort*)(ws + off); off = align256(off + (size_t)NODES * XLP * 2);
    float* xrb    = (float*)(ws + off);  off = align256(off + (size_t)NODES * WDIM * 4);
    int* counts   = (int*)(ws + off);    off = align256(off + (size_t)NODES * 4);
    int* cursor   = (int*)(ws + off);    off = align256(off + (size_t)NODES * 4);
    int* offsets  = (int*)(ws + off);    off = align256(off + (size_t)(NODES + 1) * 4);
    int* csr_src  = (int*)(ws + off);    off = align256(off + (size_t)ETOT * 4);
    size_t frag_l0_elems = (size_t)4 * 40 * 2 * 64;    // bf16x8 units
    size_t frag_ln_elems = (size_t)10 * 40 * 2 * 64;
    bf16x8* bfrag0 = (bf16x8*)(ws + off); off = align256(off + frag_l0_elems * 16);
    bf16x8* bfrag1 = (bf16x8*)(ws + off); off = align256(off + 4 * frag_ln_elems * 16);

    float* out = (float*)d_out;

    // all weight fragment pre-splits in ONE launch
    {
        int total = 4 * 40 * 64 + 4 * 10 * 40 * 64;
        make_bfrag_all<<<(total + 255) / 256, 256, 0, stream>>>(
            Wl0, Wr0, Wl, Wr, bfrag0, bfrag1, frag_ln_elems);
    }

    // CSR build
    hipMemsetAsync(counts, 0, (size_t)NODES * 4, stream);
    hipMemsetAsync(cursor, 0, (size_t)NODES * 4, stream);
    count_edges<<<(ETOT + 255) / 256, 256, 0, stream>>>(ei, counts);
    scan_kernel<<<1, 1024, 0, stream>>>(counts, offsets, NODES);
    scatter_edges<<<(ETOT + 255) / 256, 256, 0, stream>>>(ei, offsets, cursor, csr_src);

    int agg_blocks = NODES / 2;   // 2 nodes per block (NODES even)

    // layer 0: A = emb with row indirection
    gemm_mfma<<<1200, 256, 0, stream>>>(emb, x, 1, bfrag0, bl0, br0, xlb16, xrb, NODES, D0, 4);
    gat_edge_agg<<<agg_blocks, 256, 0, stream>>>(xlb16, xrb, offsets, csr_src, att0, bias0, h);

    // layers 1..4
    for (int i = 0; i < 4; i++) {
        float* dst = (i == 3) ? out : h;
        gemm_mfma<<<1200, 256, 0, stream>>>(h, nullptr, 0, bfrag1 + i * frag_ln_elems,
                                            bl + i * WDIM, br + i * WDIM,
                                            xlb16, xrb, NODES, WDIM, 10);
        gat_edge_agg<<<agg_blocks, 256, 0, stream>>>(xlb16, xrb, offsets, csr_src,
                                                     att + (size_t)i * WDIM,
                                                     bias + (size_t)i * WDIM, dst);
    }
}